// Round 5
// baseline (261.537 us; speedup 1.0000x reference)
//
#include <hip/hip_runtime.h>
#include <stdint.h>

#define SX 2048
#define SYY 2048
#define DDIM 1024
#define NBATCH 8

typedef _Float16 f16;
typedef __attribute__((ext_vector_type(4))) _Float16 h4_t;
typedef __attribute__((ext_vector_type(8))) _Float16 h8_t;
typedef __attribute__((ext_vector_type(4))) float fx4_t;

__device__ __forceinline__ void gload_lds16(const void* g, void* l) {
  __builtin_amdgcn_global_load_lds((const __attribute__((address_space(1))) void*)g,
                                   (__attribute__((address_space(3))) void*)l,
                                   16, 0, 0);
}

// ---- prep: copy x into out[:, :, 0:D] (fp32) AND convert x -> fp16 ----
__global__ __launch_bounds__(256) void k_prep_x(const float4* __restrict__ x,
                                                float* __restrict__ out,
                                                h4_t* __restrict__ x16, long n4) {
  long i = (long)blockIdx.x * blockDim.x + threadIdx.x;
  long stride = (long)gridDim.x * blockDim.x;
  for (; i < n4; i += stride) {
    long bi = i >> 8;            // / (DDIM/4)
    int dq = (int)(i & 255);
    float4 v = x[i];
    *(float4*)(out + bi * (2 * DDIM) + dq * 4) = v;
    h4_t h = { (f16)v.x, (f16)v.y, (f16)v.z, (f16)v.w };
    x16[i] = h;
  }
}

// ---- y[z][j][d] fp32 -> Y16[z][j][d] fp16 and Yt16[z][d][j] fp16 ----
__global__ __launch_bounds__(256) void k_trans(const float* __restrict__ y,
                                               f16* __restrict__ y16,
                                               f16* __restrict__ yt16) {
  __shared__ f16 tile[64][72];
  int z = blockIdx.z;
  int d0 = blockIdx.x * 64, j0 = blockIdx.y * 64;
  const float* yb = y + (size_t)z * SYY * DDIM;
  f16* y16b = y16 + (size_t)z * SYY * DDIM;
  f16* ytb = yt16 + (size_t)z * DDIM * SYY;
  int t = threadIdx.x;
  int jl = t >> 2;
  int dq = t & 3;
#pragma unroll
  for (int s = 0; s < 4; ++s) {
    int dl = dq * 16 + s * 4;
    float4 v = *(const float4*)(yb + (size_t)(j0 + jl) * DDIM + d0 + dl);
    h4_t h = { (f16)v.x, (f16)v.y, (f16)v.z, (f16)v.w };
    *(h4_t*)(y16b + (size_t)(j0 + jl) * DDIM + d0 + dl) = h;
    *(h4_t*)&tile[jl][dl] = h;
  }
  __syncthreads();
  int dl2 = t >> 2;
  int jq = t & 3;
  f16 vbuf[16] __attribute__((aligned(16)));
#pragma unroll
  for (int u = 0; u < 16; ++u) vbuf[u] = tile[jq * 16 + u][dl2];
  f16* orow = ytb + (size_t)(d0 + dl2) * SYY + j0 + jq * 16;
  *(uint4*)orow = *(const uint4*)&vbuf[0];
  *(uint4*)(orow + 8) = *(const uint4*)&vbuf[8];
}

// ==== 128x256 GEMM, 2 blocks/CU: C[m][n] = sum_k A[m][k]*B[n][k] ====
// 8 waves (2M x 4N), wave tile 64x64, BK=32, ring-3 LDS (A 3x8KB + B 3x16KB
// = 72KB -> 2 resident blocks/CU for cross-block overlap of barrier phases).
// Ledger: A(t+2) staged at subphase-a(t), B(t+3) at subphase-b(t); per-tile
// vmcnt(5) checkpoint drains exactly next tile's A,B (simulated; tail vmcnt0).
// Swizzle: LDS rows of 64B; (row, slot p) holds k-slot p^((row>>1)&3); read
// offset fr*64 + (fh^((fr>>1)&3))*16 -> each 8-lane beat covers all 32 banks.
#define PH_BAR() __builtin_amdgcn_s_barrier()

#define STAGE_A(SOFF, T) gload_lds16(aSrc + (size_t)(T) * 32, (char*)lds + (SOFF) + adst)
#define STAGE_B(SOFF, T) {                                                     \
    gload_lds16(bSrc + (size_t)(T) * 32, (char*)lds + (SOFF) + bdst);          \
    gload_lds16(bSrc2 + (size_t)(T) * 32, (char*)lds + (SOFF) + 8192 + bdst); }

#define RD_A2(SOFF, M0) {                                                      \
    af[(M0)]     = *(const h8_t*)(ldsb + (SOFF) + ardoff + (M0) * 1024);       \
    af[(M0) + 1] = *(const h8_t*)(ldsb + (SOFF) + ardoff + ((M0) + 1) * 1024); }

#define RD_B4(SOFF) { _Pragma("unroll") for (int j_ = 0; j_ < 4; ++j_)         \
    bf[j_] = *(const h8_t*)(ldsb + (SOFF) + brdoff + j_ * 1024); }

#define MMH(M0) { __builtin_amdgcn_s_setprio(1);                               \
  _Pragma("unroll") for (int i_ = 0; i_ < 2; ++i_)                             \
  _Pragma("unroll") for (int j_ = 0; j_ < 4; ++j_)                             \
    acc[(M0) + i_][j_] = __builtin_amdgcn_mfma_f32_16x16x32_f16(               \
        af[(M0) + i_], bf[j_], acc[(M0) + i_][j_], 0, 0, 0);                   \
  __builtin_amdgcn_s_setprio(0); }

__global__ __launch_bounds__(512, 4) void k_gemm8(
    const f16* __restrict__ A, long a_zs, int a_row0, int lda,
    const f16* __restrict__ B, long b_zs, int ldb,
    float* __restrict__ C, long c_zs, int c_row0, int ldc, int c_col0,
    int K, int ntm, int ntn, int nblk)
{
  __shared__ f16 lds[36864];   // 72 KiB: A slots @0/8K/16K, B slots @24K/40K/56K

  int bid = blockIdx.x;
  int id = bid;
  if ((nblk & 7) == 0) {               // bijective XCD swizzle
    int cpx = nblk >> 3;
    id = (bid & 7) * cpx + (bid >> 3);
  }
  int tpz = ntm * ntn;
  int z = id / tpz;
  int rem = id - z * tpz;
  int mt = rem / ntn;
  int ntl = rem - mt * ntn;
  int m0 = mt * 128, n0 = ntl * 256;

  const int tid = threadIdx.x;
  const int lane = tid & 63, w = tid >> 6;
  const int wr = w >> 2, wc = w & 3;
  const int fr = lane & 15, fh = lane >> 4;

  const f16* Ab = A + (size_t)z * a_zs + (size_t)(a_row0 + m0) * lda;
  const f16* Bb = B + (size_t)z * b_zs + (size_t)n0 * ldb;

  // stage sources (per-lane k pre-swizzled; LDS dest linear tid*16B)
  const int arow = tid >> 2;                         // 0..127
  const int kx = (tid & 3) ^ ((arow >> 1) & 3);
  const f16* aSrc = Ab + (size_t)arow * lda + kx * 8;
  const f16* bSrc = Bb + (size_t)arow * ldb + kx * 8;
  const f16* bSrc2 = bSrc + (size_t)128 * ldb;
  const int adst = tid * 16;     // bytes within A slot
  const int bdst = tid * 16;     // bytes within B slot unit0 (unit1 +8192)

  // read offsets
  const char* ldsb = (const char*)lds;
  const int voff = fr * 64 + ((fh ^ ((fr >> 1) & 3)) * 16);
  const int ardoff = wr * 4096 + voff;
  const int brdoff = wc * 4096 + voff;

  const int nt = K >> 5;       // K-tiles of 32

  fx4_t acc[4][4];
#pragma unroll
  for (int i = 0; i < 4; ++i)
#pragma unroll
    for (int j = 0; j < 4; ++j) {
      fx4_t zv = {0.f, 0.f, 0.f, 0.f};
      acc[i][j] = zv;
    }
  h8_t af[4], bf[4];

  int sa0 = 0, sa1 = 8192, sa2 = 16384;
  int sb0 = 24576, sb1 = 40960, sb2 = 57344;

  // prologue: A0,A1, B0,B1,B2 (8 vm ops); need tile0 (A0,B0) -> vmcnt(4)
  STAGE_A(sa0, 0); STAGE_A(sa1, 1);
  STAGE_B(sb0, 0); STAGE_B(sb1, 1); STAGE_B(sb2, 2);
  asm volatile("s_waitcnt vmcnt(4)" ::: "memory");
  PH_BAR();

  for (int t = 0; t < nt; ++t) {
    // subphase a: rd af0,af1 + bf0..3 of tile t; stage A(t+2) -> sa2
    RD_A2(sa0, 0); RD_B4(sb0);
    if (t + 2 < nt) STAGE_A(sa2, t + 2);
    PH_BAR();
    MMH(0);
    PH_BAR();
    // subphase b: rd af2,af3; stage B(t+3) -> sb0 (vacated in subphase a)
    RD_A2(sa0, 2);
    if (t + 3 < nt) STAGE_B(sb0, t + 3);
    PH_BAR();
    MMH(2);
    if (t < nt - 3) { asm volatile("s_waitcnt vmcnt(5)" ::: "memory"); }
    else            { asm volatile("s_waitcnt vmcnt(0)" ::: "memory"); }
    PH_BAR();
    // rotate ring
    int ta = sa0; sa0 = sa1; sa1 = sa2; sa2 = ta;
    int tb = sb0; sb0 = sb1; sb1 = sb2; sb2 = tb;
  }

  float* Cb = C + (size_t)z * c_zs +
              (size_t)(c_row0 + m0 + wr * 64) * ldc + c_col0 + n0 + wc * 64;
#pragma unroll
  for (int mi = 0; mi < 4; ++mi)
#pragma unroll
    for (int ni = 0; ni < 4; ++ni)
#pragma unroll
      for (int r = 0; r < 4; ++r)
        Cb[(size_t)(mi * 16 + fh * 4 + r) * ldc + ni * 16 + fr] = acc[mi][ni][r];
}

// ---- row softmax: S fp32 [nrows][SYY] -> P fp16 normalized ----
__global__ __launch_bounds__(256) void k_softmax(const float* __restrict__ S,
                                                 f16* __restrict__ P, long nrows) {
  int wv = threadIdx.x >> 6;
  int lane = threadIdx.x & 63;
  long R = (long)blockIdx.x * 4 + wv;
  if (R >= nrows) return;
  const float* srow = S + R * SYY;
  f16* prow = P + R * SYY;
  float v[32];
#pragma unroll
  for (int c = 0; c < 4; ++c) {
    float4 a = *(const float4*)(srow + c * 512 + lane * 8);
    float4 b = *(const float4*)(srow + c * 512 + lane * 8 + 4);
    v[c * 8 + 0] = a.x; v[c * 8 + 1] = a.y; v[c * 8 + 2] = a.z; v[c * 8 + 3] = a.w;
    v[c * 8 + 4] = b.x; v[c * 8 + 5] = b.y; v[c * 8 + 6] = b.z; v[c * 8 + 7] = b.w;
  }
  float m = v[0];
#pragma unroll
  for (int i = 1; i < 32; ++i) m = fmaxf(m, v[i]);
#pragma unroll
  for (int off = 32; off > 0; off >>= 1) m = fmaxf(m, __shfl_xor(m, off));
  float l = 0.f;
#pragma unroll
  for (int i = 0; i < 32; ++i) { v[i] = __expf(v[i] - m); l += v[i]; }
#pragma unroll
  for (int off = 32; off > 0; off >>= 1) l += __shfl_xor(l, off);
  float r = 1.0f / l;
  f16 h[32] __attribute__((aligned(16)));
#pragma unroll
  for (int i = 0; i < 32; ++i) h[i] = (f16)(v[i] * r);
#pragma unroll
  for (int c = 0; c < 4; ++c)
    *(uint4*)(prow + c * 512 + lane * 8) = *(const uint4*)&h[c * 8];
}

extern "C" void kernel_launch(void* const* d_in, const int* in_sizes, int n_in,
                              void* d_out, int out_size, void* d_ws, size_t ws_size,
                              hipStream_t stream) {
  (void)in_sizes; (void)n_in; (void)out_size;
  const float* x = (const float*)d_in[0];
  const float* y = (const float*)d_in[1];
  float* out = (float*)d_out;

  // ws layout per group: S(fp32) | P16 | X16 | Y16 | Yt16
  size_t per_batch = (size_t)SX * SYY * 4 + (size_t)SX * SYY * 2 +
                     (size_t)SX * DDIM * 2 + (size_t)SYY * DDIM * 2 +
                     (size_t)DDIM * SYY * 2;
  int nb = (int)(ws_size / per_batch);
  if (nb > NBATCH) nb = NBATCH;
  int CH = SX;
  if (nb < 1) {
    nb = 1;
    size_t conv = (size_t)SX * DDIM * 2 + (size_t)SYY * DDIM * 2 +
                  (size_t)DDIM * SYY * 2;
    size_t avail = ws_size > conv ? ws_size - conv : 0;
    long ch = (long)(avail / ((size_t)SYY * 6));
    ch = (ch / 256) * 256;
    if (ch < 256) ch = 256;
    if (ch > SX) ch = SX;
    CH = (int)ch;
  }

  char* w = (char*)d_ws;
  float* Sbuf = (float*)w;
  size_t off = (size_t)nb * CH * SYY * 4;
  f16* Pbuf = (f16*)(w + off); off += (size_t)nb * CH * SYY * 2;
  f16* X16 = (f16*)(w + off);  off += (size_t)nb * SX * DDIM * 2;
  f16* Y16 = (f16*)(w + off);  off += (size_t)nb * SYY * DDIM * 2;
  f16* Yt16 = (f16*)(w + off);

  for (int b0 = 0; b0 < NBATCH; b0 += nb) {
    int nbc = (NBATCH - b0 < nb) ? (NBATCH - b0) : nb;
    k_prep_x<<<2048, 256, 0, stream>>>(
        (const float4*)(x + (size_t)b0 * SX * DDIM),
        out + (size_t)b0 * SX * 2 * DDIM, (h4_t*)X16,
        (long)nbc * SX * (DDIM / 4));
    dim3 tg(DDIM / 64, SYY / 64, nbc);
    k_trans<<<tg, 256, 0, stream>>>(y + (size_t)b0 * SYY * DDIM, Y16, Yt16);

    for (int i0 = 0; i0 < SX; i0 += CH) {
      int ntm = CH / 128;
      int nblk1 = nbc * ntm * (SYY / 256);
      k_gemm8<<<nblk1, 512, 0, stream>>>(X16, (long)SX * DDIM, i0, DDIM,
                                         Y16, (long)SYY * DDIM, DDIM,
                                         Sbuf, (long)CH * SYY, 0, SYY, 0,
                                         DDIM, ntm, SYY / 256, nblk1);
      long nrows = (long)nbc * CH;
      k_softmax<<<(unsigned)((nrows + 3) / 4), 256, 0, stream>>>(Sbuf, Pbuf, nrows);
      int nblk2 = nbc * ntm * (DDIM / 256);
      k_gemm8<<<nblk2, 512, 0, stream>>>(Pbuf, (long)CH * SYY, 0, SYY,
                                         Yt16, (long)DDIM * SYY, SYY,
                                         out + (size_t)b0 * SX * 2 * DDIM,
                                         (long)SX * 2 * DDIM, i0, 2 * DDIM, DDIM,
                                         SYY, ntm, DDIM / 256, nblk2);
    }
  }
}

// Round 6
// 221.024 us; speedup vs baseline: 1.1833x; 1.1833x over previous
//
#include <hip/hip_runtime.h>
#include <stdint.h>

#define SX 2048
#define SYY 2048
#define DDIM 1024
#define NBATCH 8

typedef _Float16 f16;
typedef __attribute__((ext_vector_type(2))) _Float16 h2_t;
typedef __attribute__((ext_vector_type(4))) _Float16 h4_t;
typedef __attribute__((ext_vector_type(8))) _Float16 h8_t;
typedef __attribute__((ext_vector_type(4))) float fx4_t;

__device__ __forceinline__ void gload_lds16(const void* g, void* l) {
  __builtin_amdgcn_global_load_lds((const __attribute__((address_space(1))) void*)g,
                                   (__attribute__((address_space(3))) void*)l,
                                   16, 0, 0);
}

// ---- prep: copy x into out[:, :, 0:D] (fp32) AND convert x -> fp16 ----
__global__ __launch_bounds__(256) void k_prep_x(const float4* __restrict__ x,
                                                float* __restrict__ out,
                                                h4_t* __restrict__ x16, long n4) {
  long i = (long)blockIdx.x * blockDim.x + threadIdx.x;
  long stride = (long)gridDim.x * blockDim.x;
  for (; i < n4; i += stride) {
    long bi = i >> 8;            // / (DDIM/4)
    int dq = (int)(i & 255);
    float4 v = x[i];
    *(float4*)(out + bi * (2 * DDIM) + dq * 4) = v;
    h4_t h = { (f16)v.x, (f16)v.y, (f16)v.z, (f16)v.w };
    x16[i] = h;
  }
}

// ---- y[z][j][d] fp32 -> Y16[z][j][d] fp16 and Yt16[z][d][j] fp16 ----
__global__ __launch_bounds__(256) void k_trans(const float* __restrict__ y,
                                               f16* __restrict__ y16,
                                               f16* __restrict__ yt16) {
  __shared__ f16 tile[64][72];
  int z = blockIdx.z;
  int d0 = blockIdx.x * 64, j0 = blockIdx.y * 64;
  const float* yb = y + (size_t)z * SYY * DDIM;
  f16* y16b = y16 + (size_t)z * SYY * DDIM;
  f16* ytb = yt16 + (size_t)z * DDIM * SYY;
  int t = threadIdx.x;
  int jl = t >> 2;
  int dq = t & 3;
#pragma unroll
  for (int s = 0; s < 4; ++s) {
    int dl = dq * 16 + s * 4;
    float4 v = *(const float4*)(yb + (size_t)(j0 + jl) * DDIM + d0 + dl);
    h4_t h = { (f16)v.x, (f16)v.y, (f16)v.z, (f16)v.w };
    *(h4_t*)(y16b + (size_t)(j0 + jl) * DDIM + d0 + dl) = h;
    *(h4_t*)&tile[jl][dl] = h;
  }
  __syncthreads();
  int dl2 = t >> 2;
  int jq = t & 3;
  f16 vbuf[16] __attribute__((aligned(16)));
#pragma unroll
  for (int u = 0; u < 16; ++u) vbuf[u] = tile[jq * 16 + u][dl2];
  f16* orow = ytb + (size_t)(d0 + dl2) * SYY + j0 + jq * 16;
  *(uint4*)orow = *(const uint4*)&vbuf[0];
  *(uint4*)(orow + 8) = *(const uint4*)&vbuf[8];
}

// ==== shared 256x256 8-phase GEMM machinery (round-3 verified ledger) ====
#define PH_BAR() __builtin_amdgcn_s_barrier()

#define STAGE_A(SLOT, HALF, T) {                                               \
    const f16* s_ = aRow + (size_t)((HALF) * 64) * lda + (T) * 64;             \
    f16* d_ = lds + (SLOT) * 8192 + dstoff;                                    \
    gload_lds16(s_, d_);                                                       \
    gload_lds16(s_ + (size_t)128 * lda, d_ + 4096); }

#define STAGE_B(SLOT, HALF, T) {                                               \
    const f16* s_ = bRow + (size_t)((HALF) * 32) * ldb + (T) * 64;             \
    f16* d_ = lds + (SLOT) * 8192 + dstoff;                                    \
    gload_lds16(s_, d_);                                                       \
    gload_lds16(s_ + (size_t)128 * ldb, d_ + 4096); }

#define RD_A(PTR, CB) { _Pragma("unroll") for (int i_ = 0; i_ < 4; ++i_) {     \
    af[i_][0] = *(const h8_t*)((PTR) + (CB) + i_ * 2048 + kb0);                \
    af[i_][1] = *(const h8_t*)((PTR) + (CB) + i_ * 2048 + kb1); } }

// gemm2 variant: scale A-fragments by per-row factor fdc[MOFF + i]
#define RD_A_S(PTR, CB, MOFF) { _Pragma("unroll") for (int i_ = 0; i_ < 4; ++i_) { \
    h8_t a0 = *(const h8_t*)((PTR) + (CB) + i_ * 2048 + kb0);                  \
    h8_t a1 = *(const h8_t*)((PTR) + (CB) + i_ * 2048 + kb1);                  \
    h2_t* p0 = (h2_t*)&a0; h2_t* p1 = (h2_t*)&a1;                              \
    _Pragma("unroll") for (int q_ = 0; q_ < 4; ++q_) {                         \
      p0[q_] *= fdc[(MOFF) + i_]; p1[q_] *= fdc[(MOFF) + i_]; }                \
    af[i_][0] = a0; af[i_][1] = a1; } }

#define RD_B(PTR, CB, NH) { _Pragma("unroll") for (int j_ = 0; j_ < 2; ++j_) { \
    bf[(NH) + j_][0] = *(const h8_t*)((PTR) + (CB) + j_ * 2048 + kb0);         \
    bf[(NH) + j_][1] = *(const h8_t*)((PTR) + (CB) + j_ * 2048 + kb1); } }

#define MM(MH, NH) { __builtin_amdgcn_s_setprio(1);                            \
  _Pragma("unroll") for (int i_ = 0; i_ < 4; ++i_)                             \
  _Pragma("unroll") for (int j_ = 0; j_ < 2; ++j_) {                           \
    acc[(MH) + i_][(NH) + j_] = __builtin_amdgcn_mfma_f32_16x16x32_f16(        \
        af[i_][0], bf[(NH) + j_][0], acc[(MH) + i_][(NH) + j_], 0, 0, 0);      \
    acc[(MH) + i_][(NH) + j_] = __builtin_amdgcn_mfma_f32_16x16x32_f16(        \
        af[i_][1], bf[(NH) + j_][1], acc[(MH) + i_][(NH) + j_], 0, 0, 0); }    \
  __builtin_amdgcn_s_setprio(0); }

// tile-id decode with XCD chunking + n-major half-m ordering for L2 reuse
#define DECODE_TILE()                                                          \
  int bid = blockIdx.x;                                                        \
  int id = bid;                                                                \
  if ((nblk & 7) == 0) { int cpx = nblk >> 3; id = (bid & 7) * cpx + (bid >> 3); } \
  int tpz = ntm * ntn;                                                         \
  int z = id / tpz;                                                            \
  int rem = id - z * tpz;                                                      \
  int mt, ntl;                                                                 \
  if ((ntm & 1) == 0) {                                                        \
    int ht = tpz >> 1, hm = ntm >> 1;                                          \
    int half = rem / ht, j = rem - half * ht;                                  \
    ntl = j / hm; mt = half * hm + (j - ntl * hm);                             \
  } else { mt = rem / ntn; ntl = rem - mt * ntn; }                             \
  int m0 = mt * 256, n0 = ntl * 256;

#define GEMM_COMMON_SETUP()                                                    \
  const int tid = threadIdx.x;                                                 \
  const int lane = tid & 63, w = tid >> 6;                                     \
  const int wr = w >> 2, wc = w & 3;                                           \
  const int fr = lane & 15, fh = lane >> 4;                                    \
  const f16* Ab = A + (size_t)z * a_zs + (size_t)(a_row0 + m0) * lda;          \
  const f16* Bb = B + (size_t)z * b_zs + (size_t)n0 * ldb;                     \
  const int l0 = 8 * w + (lane >> 3);                                          \
  const int r0a = l0;                                                          \
  const int r0b = ((l0 >> 5) << 6) | (l0 & 31);                                \
  const int swz = 8 * ((lane & 7) ^ (lane >> 3));                              \
  const f16* aRow = Ab + (size_t)r0a * lda + swz;                              \
  const f16* bRow = Bb + (size_t)r0b * ldb + swz;                              \
  const int dstoff = w * 512 + lane * 8;                                       \
  const char* ldsAlo = (const char*)lds + wr * 8192 + fr * 128;                \
  const char* ldsAhi = ldsAlo + 16384;                                         \
  const char* ldsBlo = (const char*)lds + 32768 + wc * 4096 + fr * 128;        \
  const char* ldsBhi = ldsBlo + 16384;                                         \
  const int kb0 = ((0 + fh) ^ (fr & 7)) * 16;                                  \
  const int kb1 = ((4 + fh) ^ (fr & 7)) * 16;

// ==== GEMM1: S = X16 . Y16^T, fused online-softmax epilogue ====
// writes u = exp(s - m_tile) (f16) and per-(row,tile) (m,l) fp32 pairs.
__global__ __launch_bounds__(512, 2) void k_gemm1(
    const f16* __restrict__ A, long a_zs, int a_row0, int lda,
    const f16* __restrict__ B, long b_zs, int ldb,
    f16* __restrict__ U, long u_zs,
    float2* __restrict__ ML, int mrows,
    int K, int ntm, int ntn, int nblk)
{
  __shared__ f16 lds[65536];
  DECODE_TILE();
  GEMM_COMMON_SETUP();

  const int nt = K >> 6;
  const int ng = nt >> 1;

  fx4_t acc[8][4];
#pragma unroll
  for (int i = 0; i < 8; ++i)
#pragma unroll
    for (int j = 0; j < 4; ++j) { fx4_t zv = {0.f,0.f,0.f,0.f}; acc[i][j] = zv; }
  h8_t af[4][2], bf[4][2];

  STAGE_A(0, 0, 0); STAGE_A(1, 1, 0); STAGE_B(2, 0, 0); STAGE_B(3, 1, 0);
  STAGE_A(4, 0, 1); STAGE_B(6, 0, 1); STAGE_B(7, 1, 1);
  asm volatile("s_waitcnt vmcnt(6)" ::: "memory");
  PH_BAR();

  for (int g = 0; g < ng; ++g) {
    const int T1 = 2 * g + 1, T2 = 2 * g + 2, T3 = 2 * g + 3;
    const bool nl = (g < ng - 1);
    RD_A(ldsAlo, 0); RD_B(ldsBlo, 0, 0);
    STAGE_A(5, 1, T1);
    PH_BAR();
    MM(0, 0);
    PH_BAR();
    RD_B(ldsBhi, 0, 2);
    if (nl) STAGE_A(0, 0, T2);
    PH_BAR();
    MM(0, 2);
    PH_BAR();
    RD_A(ldsAhi, 0);
    if (nl) STAGE_B(2, 0, T2);
    PH_BAR();
    MM(4, 0);
    PH_BAR();
    if (nl) STAGE_B(3, 1, T2);
    PH_BAR();
    MM(4, 2);
    if (nl) { asm volatile("s_waitcnt vmcnt(6)" ::: "memory"); }
    else    { asm volatile("s_waitcnt vmcnt(0)" ::: "memory"); }
    PH_BAR();
    RD_A(ldsAlo, 65536); RD_B(ldsBlo, 65536, 0);
    if (nl) STAGE_A(1, 1, T2);
    PH_BAR();
    MM(0, 0);
    PH_BAR();
    RD_B(ldsBhi, 65536, 2);
    if (nl) STAGE_A(4, 0, T3);
    PH_BAR();
    MM(0, 2);
    PH_BAR();
    RD_A(ldsAhi, 65536);
    if (nl) STAGE_B(6, 0, T3);
    PH_BAR();
    MM(4, 0);
    PH_BAR();
    if (nl) STAGE_B(7, 1, T3);
    PH_BAR();
    MM(4, 2);
    asm volatile("s_waitcnt vmcnt(6)" ::: "memory");
    PH_BAR();
  }

  // ---- fused online-softmax epilogue (per 256-col tile t = ntl) ----
  __syncthreads();
  float* red = (float*)lds;                   // 4 x 256 floats
  const int rbase = wr * 128 + fh * 4;        // + mi*16 + rr -> local row
  float pm[8][4];
#pragma unroll
  for (int mi = 0; mi < 8; ++mi)
#pragma unroll
    for (int rr = 0; rr < 4; ++rr)
      pm[mi][rr] = fmaxf(fmaxf(acc[mi][0][rr], acc[mi][1][rr]),
                         fmaxf(acc[mi][2][rr], acc[mi][3][rr]));
#pragma unroll
  for (int off = 8; off > 0; off >>= 1)
#pragma unroll
    for (int mi = 0; mi < 8; ++mi)
#pragma unroll
      for (int rr = 0; rr < 4; ++rr)
        pm[mi][rr] = fmaxf(pm[mi][rr], __shfl_xor(pm[mi][rr], off));
  if (fr == 0)
#pragma unroll
    for (int mi = 0; mi < 8; ++mi)
#pragma unroll
      for (int rr = 0; rr < 4; ++rr)
        red[wc * 256 + rbase + mi * 16 + rr] = pm[mi][rr];
  __syncthreads();
  float mrow[8][4];
#pragma unroll
  for (int mi = 0; mi < 8; ++mi)
#pragma unroll
    for (int rr = 0; rr < 4; ++rr) {
      int r = rbase + mi * 16 + rr;
      mrow[mi][rr] = fmaxf(fmaxf(red[r], red[256 + r]),
                           fmaxf(red[512 + r], red[768 + r]));
    }
  __syncthreads();
  float ps[8][4];
#pragma unroll
  for (int mi = 0; mi < 8; ++mi)
#pragma unroll
    for (int rr = 0; rr < 4; ++rr) {
      float s = 0.f;
#pragma unroll
      for (int ni = 0; ni < 4; ++ni) {
        float e = __expf(acc[mi][ni][rr] - mrow[mi][rr]);
        acc[mi][ni][rr] = e;
        s += e;
      }
      ps[mi][rr] = s;
    }
#pragma unroll
  for (int off = 8; off > 0; off >>= 1)
#pragma unroll
    for (int mi = 0; mi < 8; ++mi)
#pragma unroll
      for (int rr = 0; rr < 4; ++rr)
        ps[mi][rr] += __shfl_xor(ps[mi][rr], off);
  if (fr == 0)
#pragma unroll
    for (int mi = 0; mi < 8; ++mi)
#pragma unroll
      for (int rr = 0; rr < 4; ++rr)
        red[wc * 256 + rbase + mi * 16 + rr] = ps[mi][rr];
  __syncthreads();
  // write u (f16)
  f16* Ub = U + (size_t)z * u_zs;
#pragma unroll
  for (int mi = 0; mi < 8; ++mi)
#pragma unroll
    for (int ni = 0; ni < 4; ++ni)
#pragma unroll
      for (int rr = 0; rr < 4; ++rr)
        Ub[(size_t)(m0 + rbase + mi * 16 + rr) * SYY +
           n0 + wc * 64 + ni * 16 + fr] = (f16)acc[mi][ni][rr];
  // write (m, l) per row for this tile
  if (wc == 0 && fr == 0) {
    float2* MLp = ML + ((size_t)z * 8 + ntl) * mrows + m0;
#pragma unroll
    for (int mi = 0; mi < 8; ++mi)
#pragma unroll
      for (int rr = 0; rr < 4; ++rr) {
        int r = rbase + mi * 16 + rr;
        float l4 = red[r] + red[256 + r] + red[512 + r] + red[768 + r];
        float2 v; v.x = mrow[mi][rr]; v.y = l4;
        MLp[r] = v;
      }
  }
}

// ---- per-row combine: 8 tiles' (m,l) -> factor_t = exp(m_t - M)/L (f16) ----
__global__ __launch_bounds__(256) void k_mlred(const float2* __restrict__ ML,
                                               f16* __restrict__ Fq,
                                               int rows, long total) {
  long idx = (long)blockIdx.x * blockDim.x + threadIdx.x;
  if (idx >= total) return;
  int z = (int)(idx / rows);
  int r = (int)(idx - (long)z * rows);
  float2 v[8];
  float M = -3.4e38f;
#pragma unroll
  for (int t = 0; t < 8; ++t) {
    v[t] = ML[((size_t)z * 8 + t) * rows + r];
    M = fmaxf(M, v[t].x);
  }
  float L = 0.f;
#pragma unroll
  for (int t = 0; t < 8; ++t) L += v[t].y * __expf(v[t].x - M);
  float inv = 1.0f / L;
#pragma unroll
  for (int t = 0; t < 8; ++t)
    Fq[((size_t)z * 8 + t) * rows + r] = (f16)(__expf(v[t].x - M) * inv);
}

// ==== GEMM2: out_right = (u * factor) . Yt^T, factor applied on A-frags ====
__global__ __launch_bounds__(512, 2) void k_gemm2(
    const f16* __restrict__ A, long a_zs, int a_row0, int lda,
    const f16* __restrict__ B, long b_zs, int ldb,
    float* __restrict__ C, long c_zs, int c_row0, int ldc, int c_col0,
    const f16* __restrict__ Fq, int mrows,
    int K, int ntm, int ntn, int nblk)
{
  __shared__ f16 lds[65536];
  DECODE_TILE();
  GEMM_COMMON_SETUP();

  const int nt = K >> 6;
  const int ng = nt >> 1;

  fx4_t acc[8][4];
#pragma unroll
  for (int i = 0; i < 8; ++i)
#pragma unroll
    for (int j = 0; j < 4; ++j) { fx4_t zv = {0.f,0.f,0.f,0.f}; acc[i][j] = zv; }
  h8_t af[4][2], bf[4][2];

  // factor base: row(mi) = m0 + wr*128 + mi*16 + fr, table [z][t][mrows]
  const f16* Fb = Fq + (size_t)z * 8 * mrows + m0 + wr * 128 + fr;
  h2_t fdc[8], fdn[8];
  // preload t=0 factors (before prologue stages; drained by prologue vmcnt(6))
#pragma unroll
  for (int i = 0; i < 8; ++i) {
    f16 fv = Fb[i * 16];
    h2_t d; d[0] = fv; d[1] = fv; fdn[i] = d;
  }

  STAGE_A(0, 0, 0); STAGE_A(1, 1, 0); STAGE_B(2, 0, 0); STAGE_B(3, 1, 0);
  STAGE_A(4, 0, 1); STAGE_B(6, 0, 1); STAGE_B(7, 1, 1);
  asm volatile("s_waitcnt vmcnt(6)" ::: "memory");
  PH_BAR();

  for (int g = 0; g < ng; ++g) {
    const int T1 = 2 * g + 1, T2 = 2 * g + 2, T3 = 2 * g + 3;
    const bool nl = (g < ng - 1);
    if ((g & 1) == 0) {
      // adopt factors for t = g>>1; prefetch t+1 (ledger-exact: these 8 loads
      // sit between the carried 6 stage-ops and slot5, so ph3's vmcnt(6)
      // drains them along with the required set)
#pragma unroll
      for (int i = 0; i < 8; ++i) fdc[i] = fdn[i];
      int tn = (g >> 1) + 1;
      if (tn < 8) {
        const f16* Fn = Fb + (size_t)tn * mrows;
#pragma unroll
        for (int i = 0; i < 8; ++i) {
          f16 fv = Fn[i * 16];
          h2_t d; d[0] = fv; d[1] = fv; fdn[i] = d;
        }
      }
    }
    RD_A_S(ldsAlo, 0, 0); RD_B(ldsBlo, 0, 0);
    STAGE_A(5, 1, T1);
    PH_BAR();
    MM(0, 0);
    PH_BAR();
    RD_B(ldsBhi, 0, 2);
    if (nl) STAGE_A(0, 0, T2);
    PH_BAR();
    MM(0, 2);
    PH_BAR();
    RD_A_S(ldsAhi, 0, 4);
    if (nl) STAGE_B(2, 0, T2);
    PH_BAR();
    MM(4, 0);
    PH_BAR();
    if (nl) STAGE_B(3, 1, T2);
    PH_BAR();
    MM(4, 2);
    if (nl) { asm volatile("s_waitcnt vmcnt(6)" ::: "memory"); }
    else    { asm volatile("s_waitcnt vmcnt(0)" ::: "memory"); }
    PH_BAR();
    RD_A_S(ldsAlo, 65536, 0); RD_B(ldsBlo, 65536, 0);
    if (nl) STAGE_A(1, 1, T2);
    PH_BAR();
    MM(0, 0);
    PH_BAR();
    RD_B(ldsBhi, 65536, 2);
    if (nl) STAGE_A(4, 0, T3);
    PH_BAR();
    MM(0, 2);
    PH_BAR();
    RD_A_S(ldsAhi, 65536, 4);
    if (nl) STAGE_B(6, 0, T3);
    PH_BAR();
    MM(4, 0);
    PH_BAR();
    if (nl) STAGE_B(7, 1, T3);
    PH_BAR();
    MM(4, 2);
    asm volatile("s_waitcnt vmcnt(6)" ::: "memory");
    PH_BAR();
  }

  float* Cb = C + (size_t)z * c_zs +
              (size_t)(c_row0 + m0 + wr * 128) * ldc + c_col0 + n0 + wc * 64;
#pragma unroll
  for (int mi = 0; mi < 8; ++mi)
#pragma unroll
    for (int ni = 0; ni < 4; ++ni)
#pragma unroll
      for (int r = 0; r < 4; ++r)
        Cb[(size_t)(mi * 16 + fh * 4 + r) * ldc + ni * 16 + fr] = acc[mi][ni][r];
}

extern "C" void kernel_launch(void* const* d_in, const int* in_sizes, int n_in,
                              void* d_out, int out_size, void* d_ws, size_t ws_size,
                              hipStream_t stream) {
  (void)in_sizes; (void)n_in; (void)out_size;
  const float* x = (const float*)d_in[0];
  const float* y = (const float*)d_in[1];
  float* out = (float*)d_out;

  // ws layout per group: U(f16) | ML(float2 x8) | Fq(f16 x8) | X16 | Y16 | Yt16
  size_t per_batch = (size_t)SX * SYY * 2 + (size_t)8 * SX * 8 + (size_t)8 * SX * 2 +
                     (size_t)SX * DDIM * 2 + (size_t)SYY * DDIM * 2 +
                     (size_t)DDIM * SYY * 2;
  int nb = (int)(ws_size / per_batch);
  if (nb > NBATCH) nb = NBATCH;
  int CH = SX;
  if (nb < 1) {
    nb = 1;
    size_t conv = (size_t)SX * DDIM * 2 + (size_t)SYY * DDIM * 2 +
                  (size_t)DDIM * SYY * 2;
    size_t avail = ws_size > conv ? ws_size - conv : 0;
    long ch = (long)(avail / ((size_t)SYY * 2 + 80));
    ch = (ch / 256) * 256;
    if (ch < 256) ch = 256;
    if (ch > SX) ch = SX;
    CH = (int)ch;
  }

  char* w = (char*)d_ws;
  f16* Ubuf = (f16*)w;            size_t off = (size_t)nb * CH * SYY * 2;
  float2* MLbuf = (float2*)(w + off); off += (size_t)nb * 8 * CH * 8;
  f16* Fqbuf = (f16*)(w + off);   off += (size_t)nb * 8 * CH * 2;
  f16* X16 = (f16*)(w + off);     off += (size_t)nb * SX * DDIM * 2;
  f16* Y16 = (f16*)(w + off);     off += (size_t)nb * SYY * DDIM * 2;
  f16* Yt16 = (f16*)(w + off);

  for (int b0 = 0; b0 < NBATCH; b0 += nb) {
    int nbc = (NBATCH - b0 < nb) ? (NBATCH - b0) : nb;
    k_prep_x<<<2048, 256, 0, stream>>>(
        (const float4*)(x + (size_t)b0 * SX * DDIM),
        out + (size_t)b0 * SX * 2 * DDIM, (h4_t*)X16,
        (long)nbc * SX * (DDIM / 4));
    dim3 tg(DDIM / 64, SYY / 64, nbc);
    k_trans<<<tg, 256, 0, stream>>>(y + (size_t)b0 * SYY * DDIM, Y16, Yt16);

    for (int i0 = 0; i0 < SX; i0 += CH) {
      int ntm = CH / 256;
      int nblk1 = nbc * ntm * (SYY / 256);
      k_gemm1<<<nblk1, 512, 0, stream>>>(X16, (long)SX * DDIM, i0, DDIM,
                                         Y16, (long)SYY * DDIM, DDIM,
                                         Ubuf, (long)CH * SYY,
                                         MLbuf, CH,
                                         DDIM, ntm, SYY / 256, nblk1);
      long rows_total = (long)nbc * CH;
      k_mlred<<<(unsigned)((rows_total + 255) / 256), 256, 0, stream>>>(
          MLbuf, Fqbuf, CH, rows_total);
      int nblk2 = nbc * ntm * (DDIM / 256);
      k_gemm2<<<nblk2, 512, 0, stream>>>(Ubuf, (long)CH * SYY, 0, SYY,
                                         Yt16, (long)DDIM * SYY, SYY,
                                         out + (size_t)b0 * SX * 2 * DDIM,
                                         (long)SX * 2 * DDIM, i0, 2 * DDIM, DDIM,
                                         Fqbuf, CH,
                                         SYY, ntm, DDIM / 256, nblk2);
    }
  }
}